// Round 1
// baseline (7495.489 us; speedup 1.0000x reference)
//
#include <hip/hip_runtime.h>
#include <stdint.h>

#define S_LEN 1024
#define B_N   128
#define E_N   10
#define H_N   256
#define L_N   4
#define G4    1024   // 4*H

using short8 = __attribute__((ext_vector_type(8))) short;
using f32x4  = __attribute__((ext_vector_type(4))) float;

__device__ __forceinline__ unsigned short f2bf(float x){
    unsigned int u = __builtin_bit_cast(unsigned int, x);
    u = (u + 0x7FFFu + ((u >> 16) & 1u)) >> 16;   // RNE
    return (unsigned short)u;
}

// ---- convert f32 weights -> bf16 ----
__global__ void k_cvt(const float* __restrict__ src, unsigned short* __restrict__ dst, int n){
    int i = blockIdx.x*256 + threadIdx.x;
    if (i < n) dst[i] = f2bf(src[i]);
}

// ---- s[t][b][e] = relu((e01[x]+p01[t]) @ f01_w.T + f01_b) ----
__global__ void k_prep_s(const int* __restrict__ x, const float* __restrict__ e01,
                         const float* __restrict__ p01, const float* __restrict__ f01w,
                         const float* __restrict__ f01b, float* __restrict__ s){
    int idx = blockIdx.x*256 + threadIdx.x;   // t*128+b
    int t = idx >> 7;
    int tok = x[idx];
    float v[E_N];
    #pragma unroll
    for (int e=0;e<E_N;e++) v[e] = e01[tok*E_N+e] + p01[t*E_N+e];
    #pragma unroll
    for (int eo=0;eo<E_N;eo++){
        float a = f01b[eo];
        #pragma unroll
        for (int e=0;e<E_N;e++) a += v[e]*f01w[eo*E_N+e];
        s[(size_t)idx*E_N+eo] = a > 0.f ? a : 0.f;
    }
}

// ---- ssum[b][e] = sum_t s[t][b][e] ----
__global__ void k_ssum(const float* __restrict__ s, float* __restrict__ ssum){
    __shared__ float red[256][E_N];
    int b = blockIdx.x; int tid = threadIdx.x;
    float acc[E_N] = {};
    for (int t = tid; t < S_LEN; t += 256){
        const float* p = s + ((size_t)t*B_N + b)*E_N;
        #pragma unroll
        for (int e=0;e<E_N;e++) acc[e] += p[e];
    }
    #pragma unroll
    for (int e=0;e<E_N;e++) red[tid][e] = acc[e];
    __syncthreads();
    for (int st=128; st>0; st>>=1){
        if (tid < st){
            #pragma unroll
            for (int e=0;e<E_N;e++) red[tid][e] += red[tid+st][e];
        }
        __syncthreads();
    }
    if (tid < E_N) ssum[b*E_N+tid] = red[0][tid];
}

// ---- h0/c0 (relu MLPs on ssum), scatter into state buffers ----
__global__ void k_init(const float* __restrict__ ssum, const float* __restrict__ f02w,
                       const float* __restrict__ f02b, const float* __restrict__ f03w,
                       const float* __restrict__ f03b,
                       unsigned short* __restrict__ Hbuf, float* __restrict__ C){
    int b = blockIdx.x, j = threadIdx.x;   // j in [0,1024)
    float sv[E_N];
    #pragma unroll
    for (int e=0;e<E_N;e++) sv[e] = ssum[b*E_N+e];
    float h = f02b[j], c = f03b[j];
    #pragma unroll
    for (int e=0;e<E_N;e++){ h += sv[e]*f02w[j*E_N+e]; c += sv[e]*f03w[j*E_N+e]; }
    h = h > 0.f ? h : 0.f;
    c = c > 0.f ? c : 0.f;
    int l = j >> 8, k = j & 255;
    // layer l is first read at wall-step w=l from parity (l&1)
    Hbuf[(((size_t)l*2 + (l&1))*B_N + b)*H_N + k] = f2bf(h);
    C[((size_t)l*B_N + b)*H_N + k] = c;
}

__global__ void k_bias(const float* __restrict__ bih, const float* __restrict__ bhh,
                       float* __restrict__ bsum){
    int i = blockIdx.x*256 + threadIdx.x;   // 4096
    bsum[i] = bih[i] + bhh[i];
}

// ---- one wavefront wall-step: all 4 layers, layer l does t = w-l ----
// grid 256 blocks: bid = (l<<6)|(bg<<3)|kj ; block = 256 thr = 4 waves (wave = gate)
__global__ __launch_bounds__(256) void k_step(
    int w,
    const float* __restrict__ s,            // [S][B][E] f32
    const unsigned short* __restrict__ Wih, // [3][1024][256] bf16 (layers 1..3)
    const unsigned short* __restrict__ Whh, // [4][1024][256] bf16
    const float* __restrict__ Wih0,         // [1024][10] f32
    const float* __restrict__ bsum,         // [4][1024] f32
    unsigned short* __restrict__ Hbuf,      // [4][2][128][256] bf16
    float* __restrict__ C,                  // [4][128][256] f32
    float* __restrict__ Hout)               // [4][128][256] f32
{
    int bid = blockIdx.x;
    int l  = bid >> 6;
    int bg = (bid >> 3) & 7;
    int kj = bid & 7;
    int t = w - l;
    if (t < 0 || t >= S_LEN) return;
    int p = w & 1, q = p ^ 1;
    int b0 = bg * 16, k0 = kj * 32;
    int tid = threadIdx.x;

    __shared__ unsigned short hx[16][264];  // h tile, pad 264 (stride 528B -> conflict-light)
    __shared__ unsigned short xx[16][264];  // x tile (layers>=1)
    __shared__ float xs[16][E_N];           // layer-0 s tile
    __shared__ float gl[16][128];           // gates tile for cell update

    {   // load h tile [16][256] bf16
        int r = tid >> 4, cseg = tid & 15;
        const unsigned short* src = Hbuf + (((size_t)l*2 + p)*B_N + b0 + r)*H_N + cseg*16;
        *(uint4*)&hx[r][cseg*16]     = *(const uint4*)(src);
        *(uint4*)&hx[r][cseg*16 + 8] = *(const uint4*)(src + 8);
    }
    if (l > 0){
        int r = tid >> 4, cseg = tid & 15;
        const unsigned short* src = Hbuf + (((size_t)(l-1)*2 + p)*B_N + b0 + r)*H_N + cseg*16;
        *(uint4*)&xx[r][cseg*16]     = *(const uint4*)(src);
        *(uint4*)&xx[r][cseg*16 + 8] = *(const uint4*)(src + 8);
    } else {
        if (tid < 16*E_N){
            int r = tid / E_N, e = tid % E_N;
            xs[r][e] = s[((size_t)t*B_N + b0 + r)*E_N + e];
        }
    }
    __syncthreads();

    int wid  = tid >> 6;     // wave == gate index (0=i,1=f,2=g,3=o)
    int lane = tid & 63;
    int cl = lane & 15, kg = lane >> 4;

    f32x4 acc0 = {0.f,0.f,0.f,0.f};
    f32x4 acc1 = {0.f,0.f,0.f,0.f};
    int j0 = wid*256 + k0 + cl;   // global gate row for n-tile 0
    int j1 = j0 + 16;             // n-tile 1
    const unsigned short* Wh0 = Whh + ((size_t)l*G4 + j0)*H_N;
    const unsigned short* Wh1 = Whh + ((size_t)l*G4 + j1)*H_N;
    const unsigned short* Wi0 = nullptr;
    const unsigned short* Wi1 = nullptr;
    if (l > 0){
        Wi0 = Wih + ((size_t)(l-1)*G4 + j0)*H_N;
        Wi1 = Wih + ((size_t)(l-1)*G4 + j1)*H_N;
    }

    #pragma unroll
    for (int kt = 0; kt < 8; kt++){
        int kk = kt*32 + kg*8;    // A: row=lane&15, k=(lane>>4)*8 ; B: col=lane&15
        short8 ah  = *(const short8*)&hx[cl][kk];
        short8 bh0 = *(const short8*)(Wh0 + kk);
        short8 bh1 = *(const short8*)(Wh1 + kk);
        acc0 = __builtin_amdgcn_mfma_f32_16x16x32_bf16(ah, bh0, acc0, 0, 0, 0);
        acc1 = __builtin_amdgcn_mfma_f32_16x16x32_bf16(ah, bh1, acc1, 0, 0, 0);
        if (l > 0){
            short8 ax  = *(const short8*)&xx[cl][kk];
            short8 bi0 = *(const short8*)(Wi0 + kk);
            short8 bi1 = *(const short8*)(Wi1 + kk);
            acc0 = __builtin_amdgcn_mfma_f32_16x16x32_bf16(ax, bi0, acc0, 0, 0, 0);
            acc1 = __builtin_amdgcn_mfma_f32_16x16x32_bf16(ax, bi1, acc1, 0, 0, 0);
        }
    }

    float bia0 = bsum[l*G4 + j0];
    float bia1 = bsum[l*G4 + j1];
    float w00[E_N], w01[E_N];
    if (l == 0){
        #pragma unroll
        for (int e=0;e<E_N;e++){ w00[e] = Wih0[j0*E_N+e]; w01[e] = Wih0[j1*E_N+e]; }
    }
    #pragma unroll
    for (int r = 0; r < 4; r++){
        int br = kg*4 + r;            // D: row=(lane>>4)*4+reg (batch), col=lane&15
        float v0 = acc0[r] + bia0;
        float v1 = acc1[r] + bia1;
        if (l == 0){
            #pragma unroll
            for (int e=0;e<E_N;e++){ v0 += xs[br][e]*w00[e]; v1 += xs[br][e]*w01[e]; }
        }
        gl[br][wid*32 + cl]      = v0;
        gl[br][wid*32 + 16 + cl] = v1;
    }
    __syncthreads();

    // cell update: 16b x 32k = 512 elements, 2 per thread
    #pragma unroll
    for (int it = 0; it < 2; it++){
        int e  = tid + it*256;
        int br = e >> 5, ko = e & 31;
        float gi = gl[br][ko];
        float gf = gl[br][32 + ko];
        float gg = gl[br][64 + ko];
        float go = gl[br][96 + ko];
        size_t off = ((size_t)l*B_N + b0 + br)*H_N + k0 + ko;
        float c  = C[off];
        float si = 1.f/(1.f + __expf(-gi));
        float sf = 1.f/(1.f + __expf(-gf));
        float sg = tanhf(gg);
        float so = 1.f/(1.f + __expf(-go));
        float cn = sf*c + si*sg;
        float hn = so*tanhf(cn);
        C[off]    = cn;
        Hout[off] = hn;
        Hbuf[(((size_t)l*2 + q)*B_N + b0 + br)*H_N + k0 + ko] = f2bf(hn);
    }
}

// ---- y[b][l*H+k] = Hout[l][b][k] ----
__global__ void k_out(const float* __restrict__ Hout, float* __restrict__ y){
    int i = blockIdx.x*256 + threadIdx.x;  // 131072
    int b = i >> 10, j = i & 1023;
    int l = j >> 8, k = j & 255;
    y[i] = Hout[((size_t)l*B_N + b)*H_N + k];
}

extern "C" void kernel_launch(void* const* d_in, const int* in_sizes, int n_in,
                              void* d_out, int out_size, void* d_ws, size_t ws_size,
                              hipStream_t stream) {
    const int*   x      = (const int*)  d_in[0];
    const float* e01    = (const float*)d_in[1];
    const float* p01    = (const float*)d_in[2];
    const float* f01w   = (const float*)d_in[3];
    const float* f01b   = (const float*)d_in[4];
    const float* f02w   = (const float*)d_in[5];
    const float* f02b   = (const float*)d_in[6];
    const float* f03w   = (const float*)d_in[7];
    const float* f03b   = (const float*)d_in[8];
    const float* Wih0   = (const float*)d_in[9];
    const float* WihR   = (const float*)d_in[10];  // [3][1024][256]
    const float* Whh    = (const float*)d_in[11];  // [4][1024][256]
    const float* bih    = (const float*)d_in[12];
    const float* bhh    = (const float*)d_in[13];
    float* y = (float*)d_out;

    // workspace carve (floats first, then ushort)
    float* s_buf = (float*)d_ws;                         // 1,310,720 f
    float* ssum  = s_buf + (size_t)S_LEN*B_N*E_N;        // 1,280 f
    float* bsum  = ssum + B_N*E_N;                       // 4,096 f
    float* Cst   = bsum + L_N*G4;                        // 131,072 f
    float* Hout  = Cst  + L_N*B_N*H_N;                   // 131,072 f
    unsigned short* Hbuf = (unsigned short*)(Hout + L_N*B_N*H_N);  // 262,144 us
    unsigned short* WbHH = Hbuf + (size_t)L_N*2*B_N*H_N;           // 1,048,576 us
    unsigned short* WbIH = WbHH + (size_t)L_N*G4*H_N;              // 786,432 us

    // weight conversion (runs every call; cheap)
    k_cvt<<<dim3(4096), dim3(256), 0, stream>>>(Whh,  WbHH, L_N*G4*H_N);
    k_cvt<<<dim3(3072), dim3(256), 0, stream>>>(WihR, WbIH, (L_N-1)*G4*H_N);

    // prologue
    k_prep_s<<<dim3((S_LEN*B_N)/256), dim3(256), 0, stream>>>(x, e01, p01, f01w, f01b, s_buf);
    k_ssum  <<<dim3(B_N), dim3(256), 0, stream>>>(s_buf, ssum);
    k_init  <<<dim3(B_N), dim3(1024), 0, stream>>>(ssum, f02w, f02b, f03w, f03b, Hbuf, Cst);
    k_bias  <<<dim3(16), dim3(256), 0, stream>>>(bih, bhh, bsum);

    // wavefront over (layer, time): 1027 wall-steps
    for (int w = 0; w < S_LEN + L_N - 1; ++w){
        k_step<<<dim3(256), dim3(256), 0, stream>>>(w, s_buf, WbIH, WbHH, Wih0, bsum,
                                                    Hbuf, Cst, Hout);
    }

    // epilogue
    k_out<<<dim3((B_N*G4)/256), dim3(256), 0, stream>>>(Hout, y);
}